// Round 1
// baseline (91.337 us; speedup 1.0000x reference)
//
#include <hip/hip_runtime.h>

#define BB 16
#define MM 32
#define KK 20
#define AA 8
#define TT 30
#define TD 60          // T*D
#define TDP 62         // padded LDS stride (2-way bank aliasing = free)
#define NPAIR (KK*KK)  // 400

// One block per (b, a, m): computes chamfer partial and gt-min partial.
__global__ __launch_bounds__(256) void imle_part_kernel(
    const float* __restrict__ gen,   // B M K A T D
    const float* __restrict__ tgt,   // B K A T D
    const float* __restrict__ gt,    // B A T D
    float* __restrict__ ws_cham,     // [B][M][A]
    float* __restrict__ ws_gt)       // [B][M][A]
{
    __shared__ float sg[KK][TDP];
    __shared__ float st[KK][TDP];
    __shared__ float sgt[TD];
    __shared__ float pd[NPAIR];
    __shared__ float dgt[KK];
    __shared__ float rowmin[KK], colmin[KK];

    const int blk = blockIdx.x;
    const int m = blk % MM;
    const int a = (blk / MM) % AA;
    const int b = blk / (MM * AA);
    const int tid = threadIdx.x;

    // gen[b][m][k][a][t][d]; per-k trajectory is 60 contiguous floats
    const float* gbase = gen + (((size_t)b * MM + m) * KK * AA + a) * TD;
    for (int idx = tid; idx < KK * TD; idx += 256) {
        int k = idx / TD, r = idx % TD;
        sg[k][r] = 50.0f * gbase[(size_t)k * AA * TD + r];
    }
    // tgt[b][k][a][t][d]
    const float* tbase = tgt + ((size_t)b * KK * AA + a) * TD;
    for (int idx = tid; idx < KK * TD; idx += 256) {
        int k = idx / TD, r = idx % TD;
        st[k][r] = 50.0f * tbase[(size_t)k * AA * TD + r];
    }
    // gt[b][a][t][d] (already metric scale)
    if (tid < TD) sgt[tid] = gt[((size_t)b * AA + a) * TD + tid];
    __syncthreads();

    // pairwise pd[k][k'] = mean_T dist; threads 0..143 do 2 pairs, rest 1
    for (int p = tid; p < NPAIR; p += 256) {
        const int k  = p / KK;
        const int kp = p % KK;
        const float2* g2 = (const float2*)&sg[k][0];
        const float2* t2 = (const float2*)&st[kp][0];
        float s = 0.f;
#pragma unroll
        for (int t = 0; t < TT; ++t) {
            float2 gv = g2[t];
            float2 tv = t2[t];
            float dx = gv.x - tv.x;
            float dy = gv.y - tv.y;
            s += __builtin_amdgcn_sqrtf(dx * dx + dy * dy);
        }
        pd[p] = s * (1.0f / TT);
    }
    // gt distances per gen-k
    if (tid < KK) {
        const float2* g2 = (const float2*)&sg[tid][0];
        const float2* q2 = (const float2*)&sgt[0];
        float s = 0.f;
#pragma unroll
        for (int t = 0; t < TT; ++t) {
            float2 gv = g2[t];
            float2 qv = q2[t];
            float dx = gv.x - qv.x;
            float dy = gv.y - qv.y;
            s += __builtin_amdgcn_sqrtf(dx * dx + dy * dy);
        }
        dgt[tid] = s * (1.0f / TT);
    }
    __syncthreads();

    if (tid < KK) {
        float rm = pd[tid * KK + 0];
        float cm = pd[0 * KK + tid];
        for (int j = 1; j < KK; ++j) {
            rm = fminf(rm, pd[tid * KK + j]);
            cm = fminf(cm, pd[j * KK + tid]);
        }
        rowmin[tid] = rm;
        colmin[tid] = cm;
    }
    __syncthreads();

    if (tid == 0) {
        float sr = 0.f, sc = 0.f, gm = dgt[0];
        for (int j = 0; j < KK; ++j) {
            sr += rowmin[j];
            sc += colmin[j];
            gm = fminf(gm, dgt[j]);
        }
        const size_t o = ((size_t)b * MM + m) * AA + a;
        ws_cham[o] = (sr + sc) * (1.0f / KK);  // mean_k min_k' + mean_k' min_k
        ws_gt[o]   = gm;                        // min_k mean_T dist(gen, gt)
    }
}

// Single block: mean over A, min over M, mean over B, write 3 outputs.
__global__ __launch_bounds__(512) void imle_final_kernel(
    const float* __restrict__ ws_cham,
    const float* __restrict__ ws_gt,
    float* __restrict__ out)
{
    __shared__ float ch[BB * MM], gv[BB * MM];
    __shared__ float mch[BB], mgt[BB];
    const int tid = threadIdx.x;  // 512 == B*M
    const int b = tid / MM, m = tid % MM;

    float sc = 0.f, sg = 0.f;
#pragma unroll
    for (int a = 0; a < AA; ++a) {
        sc += ws_cham[((size_t)b * MM + m) * AA + a];
        sg += ws_gt[((size_t)b * MM + m) * AA + a];
    }
    ch[tid] = sc * (1.0f / AA);
    gv[tid] = sg * (1.0f / AA);
    __syncthreads();

    if (tid < BB) {
        float c = ch[tid * MM], g = gv[tid * MM];
        for (int j = 1; j < MM; ++j) {
            c = fminf(c, ch[tid * MM + j]);
            g = fminf(g, gv[tid * MM + j]);
        }
        mch[tid] = c;
        mgt[tid] = g;
    }
    __syncthreads();

    if (tid == 0) {
        float lc = 0.f, lg = 0.f;
        for (int j = 0; j < BB; ++j) { lc += mch[j]; lg += mgt[j]; }
        lc *= (1.0f / BB);
        lg *= (1.0f / BB);
        out[0] = lc + lg;
        out[1] = lc;
        out[2] = lg;
    }
}

extern "C" void kernel_launch(void* const* d_in, const int* in_sizes, int n_in,
                              void* d_out, int out_size, void* d_ws, size_t ws_size,
                              hipStream_t stream) {
    const float* gen = (const float*)d_in[0];
    const float* tgt = (const float*)d_in[1];
    const float* gt  = (const float*)d_in[2];
    float* ws_cham = (float*)d_ws;                 // B*M*A floats
    float* ws_gt   = ws_cham + BB * MM * AA;       // B*M*A floats
    float* out     = (float*)d_out;

    imle_part_kernel<<<BB * AA * MM, 256, 0, stream>>>(gen, tgt, gt, ws_cham, ws_gt);
    imle_final_kernel<<<1, 512, 0, stream>>>(ws_cham, ws_gt, out);
}

// Round 2
// 85.917 us; speedup vs baseline: 1.0631x; 1.0631x over previous
//
#include <hip/hip_runtime.h>
#include <float.h>

#define BB 16
#define MM 32
#define KK 20
#define AA 8
#define TT 30
#define TD 60          // T*D floats per trajectory
#define NS 15          // float4 steps per trajectory (2 t-steps each)
#define S4 17          // padded row stride in float4 units (68 floats, 16B-aligned rows)

// One block = 4 m's (one wave each) for a fixed (b, a).
// Per wave: 4x2 (k x kp) register tile per lane -> 50 active lanes cover 20x20 pairs.
__global__ __launch_bounds__(256) void imle_part_kernel(
    const float* __restrict__ gen,   // B M K A T D
    const float* __restrict__ tgt,   // B K A T D
    const float* __restrict__ gt,    // B A T D
    float* __restrict__ ws_cham,     // [B][M][A]
    float* __restrict__ ws_gt)       // [B][M][A]
{
    __shared__ float4 sg[4][KK][S4];   // 4 m-slices of gen, scaled by 50
    __shared__ float4 st[KK][S4];      // target tile, scaled by 50
    __shared__ float4 sq[NS + 1];      // gt trajectory (metric scale)
    __shared__ float  pd[4][KK][KK];   // per-m pairwise mean distances

    const int blk = blockIdx.x;        // grid = B*A*(M/4) = 1024
    const int mg = blk & 7;            // m-group (M/4 = 8)
    const int a  = (blk >> 3) & 7;
    const int b  = blk >> 6;
    const int m0 = mg * 4;
    const int tid = threadIdx.x;

    // ---- stage gen: 4m x 20k rows of 15 float4 (rows 16B-aligned: 60 floats) ----
    for (int idx = tid; idx < 80 * NS; idx += 256) {
        int row = idx / NS, q = idx - row * NS;
        int mi = row / KK, k = row - mi * KK;
        const float4* src = (const float4*)(gen +
            (size_t)(((b * MM + m0 + mi) * KK + k) * AA + a) * TD);
        float4 v = src[q];
        v.x *= 50.f; v.y *= 50.f; v.z *= 50.f; v.w *= 50.f;
        sg[mi][k][q] = v;
    }
    // ---- stage tgt: 20 rows x 15 float4 ----
    for (int idx = tid; idx < KK * NS; idx += 256) {
        int k = idx / NS, q = idx - k * NS;
        const float4* src = (const float4*)(tgt +
            (size_t)((b * KK + k) * AA + a) * TD);
        float4 v = src[q];
        v.x *= 50.f; v.y *= 50.f; v.z *= 50.f; v.w *= 50.f;
        st[k][q] = v;
    }
    // ---- stage gt ----
    if (tid < NS) {
        sq[tid] = ((const float4*)(gt + (size_t)(b * AA + a) * TD))[tid];
    }
    __syncthreads();

    const int w = tid >> 6;        // wave id -> m index offset
    const int lane = tid & 63;

    // ---- pairwise distances, 4x2 register tile ----
    if (lane < 50) {
        const int tk  = lane / 10;       // 0..4  -> k0 = 4*tk
        const int tkp = lane - tk * 10;  // 0..9  -> kp0 = 2*tkp
        const int k0  = tk * 4;
        const int kp0 = tkp * 2;
        float acc[4][2] = {{0.f, 0.f}, {0.f, 0.f}, {0.f, 0.f}, {0.f, 0.f}};
        for (int s = 0; s < NS; ++s) {
            float4 g0 = sg[w][k0 + 0][s];
            float4 g1 = sg[w][k0 + 1][s];
            float4 g2 = sg[w][k0 + 2][s];
            float4 g3 = sg[w][k0 + 3][s];
            float4 t0 = st[kp0 + 0][s];
            float4 t1 = st[kp0 + 1][s];
            float4 gv[4] = {g0, g1, g2, g3};
            float4 tv[2] = {t0, t1};
#pragma unroll
            for (int i = 0; i < 4; ++i) {
#pragma unroll
                for (int j = 0; j < 2; ++j) {
                    float dx1 = gv[i].x - tv[j].x;
                    float dy1 = gv[i].y - tv[j].y;
                    float dx2 = gv[i].z - tv[j].z;
                    float dy2 = gv[i].w - tv[j].w;
                    acc[i][j] += __builtin_amdgcn_sqrtf(dx1 * dx1 + dy1 * dy1)
                               + __builtin_amdgcn_sqrtf(dx2 * dx2 + dy2 * dy2);
                }
            }
        }
        const float inv_t = 1.0f / TT;
#pragma unroll
        for (int i = 0; i < 4; ++i) {
            // pd row is contiguous; kp0 even -> 8B-aligned float2 store
            float2* dst = (float2*)&pd[w][k0 + i][kp0];
            *dst = make_float2(acc[i][0] * inv_t, acc[i][1] * inv_t);
        }
    }
    __syncthreads();

    // ---- row/col mins + sum over k (per wave / per m) ----
    float v = 0.f;
    if (lane < KK) {
        const float2* row2 = (const float2*)&pd[w][lane][0];
        float2 r0 = row2[0];
        float rm = fminf(r0.x, r0.y);
#pragma unroll
        for (int j = 1; j < 10; ++j) {
            float2 r = row2[j];
            rm = fminf(rm, fminf(r.x, r.y));
        }
        float cm = pd[w][0][lane];
#pragma unroll
        for (int j = 1; j < KK; ++j) cm = fminf(cm, pd[w][j][lane]);
        v = rm + cm;
    }
    // butterfly sum over lanes 0..31 (lanes >=20 contribute 0)
#pragma unroll
    for (int off = 16; off > 0; off >>= 1) v += __shfl_xor(v, off, 32);

    // ---- gt nearest-neighbor term ----
    float dg = FLT_MAX;
    if (lane < KK) {
        float s = 0.f;
#pragma unroll
        for (int ss = 0; ss < NS; ++ss) {
            float4 g = sg[w][lane][ss];
            float4 q = sq[ss];
            float dx1 = g.x - q.x, dy1 = g.y - q.y;
            float dx2 = g.z - q.z, dy2 = g.w - q.w;
            s += __builtin_amdgcn_sqrtf(dx1 * dx1 + dy1 * dy1)
               + __builtin_amdgcn_sqrtf(dx2 * dx2 + dy2 * dy2);
        }
        dg = s * (1.0f / TT);
    }
#pragma unroll
    for (int off = 16; off > 0; off >>= 1) dg = fminf(dg, __shfl_xor(dg, off, 32));

    if (lane == 0) {
        const size_t o = ((size_t)b * MM + (m0 + w)) * AA + a;
        ws_cham[o] = v * (1.0f / KK);
        ws_gt[o]   = dg;
    }
}

// Single block: mean over A, min over M, mean over B, write 3 outputs.
__global__ __launch_bounds__(512) void imle_final_kernel(
    const float* __restrict__ ws_cham,
    const float* __restrict__ ws_gt,
    float* __restrict__ out)
{
    __shared__ float ch[BB * MM], gv[BB * MM];
    __shared__ float mch[BB], mgt[BB];
    const int tid = threadIdx.x;  // 512 == B*M
    const int b = tid / MM, m = tid % MM;

    float sc = 0.f, sg = 0.f;
#pragma unroll
    for (int a = 0; a < AA; ++a) {
        sc += ws_cham[((size_t)b * MM + m) * AA + a];
        sg += ws_gt[((size_t)b * MM + m) * AA + a];
    }
    ch[tid] = sc * (1.0f / AA);
    gv[tid] = sg * (1.0f / AA);
    __syncthreads();

    if (tid < BB) {
        float c = ch[tid * MM], g = gv[tid * MM];
        for (int j = 1; j < MM; ++j) {
            c = fminf(c, ch[tid * MM + j]);
            g = fminf(g, gv[tid * MM + j]);
        }
        mch[tid] = c;
        mgt[tid] = g;
    }
    __syncthreads();

    if (tid == 0) {
        float lc = 0.f, lg = 0.f;
        for (int j = 0; j < BB; ++j) { lc += mch[j]; lg += mgt[j]; }
        lc *= (1.0f / BB);
        lg *= (1.0f / BB);
        out[0] = lc + lg;
        out[1] = lc;
        out[2] = lg;
    }
}

extern "C" void kernel_launch(void* const* d_in, const int* in_sizes, int n_in,
                              void* d_out, int out_size, void* d_ws, size_t ws_size,
                              hipStream_t stream) {
    const float* gen = (const float*)d_in[0];
    const float* tgt = (const float*)d_in[1];
    const float* gt  = (const float*)d_in[2];
    float* ws_cham = (float*)d_ws;                 // B*M*A floats
    float* ws_gt   = ws_cham + BB * MM * AA;       // B*M*A floats
    float* out     = (float*)d_out;

    imle_part_kernel<<<BB * AA * (MM / 4), 256, 0, stream>>>(gen, tgt, gt, ws_cham, ws_gt);
    imle_final_kernel<<<1, 512, 0, stream>>>(ws_cham, ws_gt, out);
}